// Round 1
// baseline (1425.560 us; speedup 1.0000x reference)
//
#include <hip/hip_runtime.h>
#include <hip/hip_bf16.h>

// Problem constants (from setup_inputs): B=4, N=4096, C=768, H=W=128, N0=H*W
#define BB 4
#define NN 4096
#define CC 768
#define HH 128
#define WW 128
#define N0 (HH * WW)          // 16384
#define HW (HH * WW)
#define EPS 1e-6f

// ---------------------------------------------------------------------------
// K1: per-sample pixel index, pixel counts, token weight sums
// one thread per (b, n0)
__global__ void k1_build_idx(const float* __restrict__ loc,
                             const int* __restrict__ idx_agg,
                             const float* __restrict__ agg_w,
                             int* __restrict__ idx_hw,
                             float* __restrict__ cnts,
                             float* __restrict__ tok_w) {
    int i = blockIdx.x * blockDim.x + threadIdx.x;   // 0 .. B*N0-1
    if (i >= BB * N0) return;
    float lx = loc[2 * i + 0];
    float ly = loc[2 * i + 1];
    float fx = 0.5f * (lx + 1.0f) * (float)WW - 0.5f;
    float fy = 0.5f * (ly + 1.0f) * (float)HH - 0.5f;
    int px = (int)rintf(fx);                         // round-half-even == jnp.round
    int py = (int)rintf(fy);
    px = min(max(px, 0), WW - 1);
    py = min(max(py, 0), HH - 1);
    int pix = py * WW + px;
    idx_hw[i] = pix;
    int b = i >> 14;                                 // N0 = 16384
    atomicAdd(&cnts[b * HW + pix], 1.0f);
    atomicAdd(&tok_w[b * NN + idx_agg[i]], agg_w[i]);
}

// ---------------------------------------------------------------------------
// K2: scatter token features into pixel sums.
// one block per (b, n0); 192 threads x float4 = 768 channels
__global__ void k2_scatter_feats(const float* __restrict__ x,
                                 const int* __restrict__ idx_agg,
                                 const int* __restrict__ idx_hw,
                                 float* __restrict__ sums) {
    int i = blockIdx.x;                              // b*N0 + n0
    int b = i >> 14;
    int tok = idx_agg[i];
    int pix = idx_hw[i];
    const float4* src =
        (const float4*)(x + ((size_t)(b * NN + tok)) * CC);
    float* dst = sums + ((size_t)(b * HW + pix)) * CC;
    int c4 = threadIdx.x;                            // 0..191
    float4 v = src[c4];
    atomicAdd(dst + 4 * c4 + 0, v.x);
    atomicAdd(dst + 4 * c4 + 1, v.y);
    atomicAdd(dst + 4 * c4 + 2, v.z);
    atomicAdd(dst + 4 * c4 + 3, v.w);
}

// ---------------------------------------------------------------------------
// K3: fused depthwise 3x3 conv (at sampled pixel) + bias + gather + weighted
//     scatter into token sums.  one block per (b, n0); 256 threads x 3 chans
__global__ void k3_conv_gather_scatter(const float* __restrict__ sums,
                                       const float* __restrict__ cnts,
                                       const int* __restrict__ idx_hw,
                                       const int* __restrict__ idx_agg,
                                       const float* __restrict__ agg_w,
                                       const float* __restrict__ w_dw,
                                       const float* __restrict__ b_dw,
                                       float* __restrict__ tok_sum) {
    int i = blockIdx.x;                              // b*N0 + n0
    int b = i >> 14;
    int pix = idx_hw[i];
    int ph = pix >> 7;                               // W = 128
    int pw = pix & 127;
    int c0 = threadIdx.x * 3;

    float acc0 = b_dw[c0 + 0];
    float acc1 = b_dw[c0 + 1];
    float acc2 = b_dw[c0 + 2];

#pragma unroll
    for (int t = 0; t < 9; ++t) {
        int ky = t / 3 - 1;
        int kx = t % 3 - 1;
        int py = ph + ky;
        int px = pw + kx;
        if (py >= 0 && py < HH && px >= 0 && px < WW) {
            int p = b * HW + py * WW + px;
            float inv = 1.0f / (cnts[p] + EPS);      // broadcast (uniform addr)
            const float* s = sums + (size_t)p * CC + c0;
            acc0 += s[0] * inv * w_dw[(c0 + 0) * 9 + t];
            acc1 += s[1] * inv * w_dw[(c0 + 1) * 9 + t];
            acc2 += s[2] * inv * w_dw[(c0 + 2) * 9 + t];
        }
    }
    float aw = agg_w[i];
    float* dst = tok_sum + ((size_t)(b * NN + idx_agg[i])) * CC + c0;
    atomicAdd(dst + 0, acc0 * aw);
    atomicAdd(dst + 1, acc1 * aw);
    atomicAdd(dst + 2, acc2 * aw);
}

// ---------------------------------------------------------------------------
// K4: finalize  out = tok_sum/(tok_w+eps) + x*w_skip   (float4)
__global__ void k4_finalize(const float* __restrict__ x,
                            const float* __restrict__ tok_sum,
                            const float* __restrict__ tok_w,
                            const float* __restrict__ w_skip,
                            float* __restrict__ out) {
    size_t tid = (size_t)blockIdx.x * blockDim.x + threadIdx.x;  // B*N*C/4
    size_t total = (size_t)BB * NN * (CC / 4);
    if (tid >= total) return;
    int c4 = (int)(tid % (CC / 4));
    size_t bn = tid / (CC / 4);
    float inv = 1.0f / (tok_w[bn] + EPS);
    float4 ts = ((const float4*)tok_sum)[tid];
    float4 xv = ((const float4*)x)[tid];
    float4 ws = ((const float4*)w_skip)[c4];
    float4 o;
    o.x = ts.x * inv + xv.x * ws.x;
    o.y = ts.y * inv + xv.y * ws.y;
    o.z = ts.z * inv + xv.z * ws.z;
    o.w = ts.w * inv + xv.w * ws.w;
    ((float4*)out)[tid] = o;
}

// ---------------------------------------------------------------------------
extern "C" void kernel_launch(void* const* d_in, const int* in_sizes, int n_in,
                              void* d_out, int out_size, void* d_ws, size_t ws_size,
                              hipStream_t stream) {
    const float* x        = (const float*)d_in[0];   // [B,N,C]
    const float* loc      = (const float*)d_in[1];   // [B,N0,2]
    const int*   idx_agg  = (const int*)d_in[2];     // [B,N0]
    const float* agg_w    = (const float*)d_in[3];   // [B,N0]
    // d_in[4] = H, d_in[5] = W (scalars; shapes hardcoded)
    const float* w_dw     = (const float*)d_in[6];   // [C,1,3,3]
    const float* b_dw     = (const float*)d_in[7];   // [C]
    const float* w_skip   = (const float*)d_in[8];   // [C]
    float* out = (float*)d_out;

    // workspace layout
    char* ws = (char*)d_ws;
    size_t off = 0;
    int* idx_hw = (int*)(ws + off);      off += (size_t)BB * N0 * 4;          // 256 KB
    float* cnts = (float*)(ws + off);    off += (size_t)BB * HW * 4;          // 256 KB
    float* tok_w = (float*)(ws + off);   off += (size_t)BB * NN * 4;          // 64 KB
    float* tok_sum = (float*)(ws + off); off += (size_t)BB * NN * CC * 4;     // 50 MB
    float* sums = (float*)(ws + off);    off += (size_t)BB * HW * CC * 4;     // 201 MB
    size_t zero_bytes = off;

    // zero all accumulators (harness poisons ws with 0xAA; no re-poison between replays)
    hipMemsetAsync(d_ws, 0, zero_bytes, stream);

    // K1: pixel idx + counts + token weights
    {
        int threads = 256;
        int blocks = (BB * N0 + threads - 1) / threads;
        hipLaunchKernelGGL(k1_build_idx, dim3(blocks), dim3(threads), 0, stream,
                           loc, idx_agg, agg_w, idx_hw, cnts, tok_w);
    }
    // K2: scatter features into pixel map
    hipLaunchKernelGGL(k2_scatter_feats, dim3(BB * N0), dim3(CC / 4), 0, stream,
                       x, idx_agg, idx_hw, sums);
    // K3: fused conv + gather + token scatter
    hipLaunchKernelGGL(k3_conv_gather_scatter, dim3(BB * N0), dim3(CC / 3), 0, stream,
                       sums, cnts, idx_hw, idx_agg, agg_w, w_dw, b_dw, tok_sum);
    // K4: finalize
    {
        size_t total = (size_t)BB * NN * (CC / 4);
        int threads = 256;
        int blocks = (int)((total + threads - 1) / threads);
        hipLaunchKernelGGL(k4_finalize, dim3(blocks), dim3(threads), 0, stream,
                           x, tok_sum, tok_w, w_skip, out);
    }
}

// Round 2
// 393.577 us; speedup vs baseline: 3.6221x; 3.6221x over previous
//
#include <hip/hip_runtime.h>
#include <hip/hip_bf16.h>

// Problem constants: B=4, N=4096, C=768, H=W=128, N0=H*W=16384
#define BB 4
#define NN 4096
#define CC 768
#define HH 128
#define WW 128
#define N0 (HH * WW)
#define HW (HH * WW)
#define EPS 1e-6f
#define NSAMP (BB * N0)          // 65536
#define NPIX  (BB * HW)          // 65536
#define NTOK  (BB * NN)          // 16384

// ---------------------------------------------------------------------------
// bf16 <-> f32 helpers (storage type ushort)
__device__ inline float bf2f(ushort u) {
    unsigned v = ((unsigned)u) << 16;
    return __uint_as_float(v);
}
__device__ inline ushort f2bf(float f) {
    __hip_bfloat16 h = __float2bfloat16(f);   // RNE
    return *reinterpret_cast<ushort*>(&h);
}

template <typename T> struct VecIO;
template <> struct VecIO<float> {
    static __device__ float4 load(const float* base, int c4) {
        return ((const float4*)base)[c4];
    }
    static __device__ void store(float* base, int c4, float4 v) {
        ((float4*)base)[c4] = v;
    }
};
template <> struct VecIO<ushort> {
    static __device__ float4 load(const ushort* base, int c4) {
        ushort4 u = ((const ushort4*)base)[c4];
        float4 r;
        r.x = bf2f(u.x); r.y = bf2f(u.y); r.z = bf2f(u.z); r.w = bf2f(u.w);
        return r;
    }
    static __device__ void store(ushort* base, int c4, float4 v) {
        ushort4 u;
        u.x = f2bf(v.x); u.y = f2bf(v.y); u.z = f2bf(v.z); u.w = f2bf(v.w);
        ((ushort4*)base)[c4] = u;
    }
};

// ---------------------------------------------------------------------------
// K0a: pixel index per sample + integer counts per pixel segment and token segment
__global__ void k_idx(const float* __restrict__ loc,
                      const int* __restrict__ idx_agg,
                      int* __restrict__ idx_hw,
                      int* __restrict__ count_pix,
                      int* __restrict__ count_tok) {
    int i = blockIdx.x * blockDim.x + threadIdx.x;
    if (i >= NSAMP) return;
    float lx = loc[2 * i + 0];
    float ly = loc[2 * i + 1];
    float fx = 0.5f * (lx + 1.0f) * (float)WW - 0.5f;
    float fy = 0.5f * (ly + 1.0f) * (float)HH - 0.5f;
    int px = (int)rintf(fx);                 // round-half-even == jnp.round
    int py = (int)rintf(fy);
    px = min(max(px, 0), WW - 1);
    py = min(max(py, 0), HH - 1);
    int pix = py * WW + px;
    idx_hw[i] = pix;
    int b = i >> 14;                         // N0 = 16384
    atomicAdd(&count_pix[(b << 14) + pix], 1);
    atomicAdd(&count_tok[(b << 12) + idx_agg[i]], 1);
}

// ---------------------------------------------------------------------------
// K0b: one-block exclusive scan (n <= 1024*chunk)
__global__ void k_scan_excl(const int* __restrict__ cnt, int* __restrict__ off, int n) {
    __shared__ int sh[1024];
    int t = threadIdx.x;                     // 1024 threads
    int chunk = (n + 1023) >> 10;
    int lo = t * chunk;
    int hi = min(n, lo + chunk);
    int s = 0;
    for (int k = lo; k < hi; ++k) s += cnt[k];
    sh[t] = s;
    __syncthreads();
    for (int d = 1; d < 1024; d <<= 1) {
        int v = (t >= d) ? sh[t - d] : 0;
        __syncthreads();
        sh[t] += v;
        __syncthreads();
    }
    int run = (t == 0) ? 0 : sh[t - 1];      // exclusive prefix of this chunk
    for (int k = lo; k < hi; ++k) {
        off[k] = run;
        run += cnt[k];
    }
}

// ---------------------------------------------------------------------------
// K0c: fill CSR sample lists (pixel-ordered and token-ordered)
__global__ void k_fill(const int* __restrict__ idx_hw,
                       const int* __restrict__ idx_agg,
                       const int* __restrict__ off_pix, int* __restrict__ fill_pix,
                       int* __restrict__ list_pix,
                       const int* __restrict__ off_tok, int* __restrict__ fill_tok,
                       int* __restrict__ list_tok) {
    int i = blockIdx.x * blockDim.x + threadIdx.x;
    if (i >= NSAMP) return;
    int b = i >> 14;
    int sp = (b << 14) + idx_hw[i];
    int p = atomicAdd(&fill_pix[sp], 1);
    list_pix[off_pix[sp] + p] = i;
    int st = (b << 12) + idx_agg[i];
    int q = atomicAdd(&fill_tok[st], 1);
    list_tok[off_tok[st] + q] = i;
}

// ---------------------------------------------------------------------------
// K1: build normalized pixel map via gather (no atomics).  grid = NPIX, 192 thr
template <typename T1>
__global__ __launch_bounds__(192) void k_xmap(const float* __restrict__ x,
                                              const int* __restrict__ idx_agg,
                                              const int* __restrict__ count_pix,
                                              const int* __restrict__ off_pix,
                                              const int* __restrict__ list_pix,
                                              T1* __restrict__ xm) {
    int bi = blockIdx.x;                     // b*HW + pix
    int b = bi >> 14;
    int c4 = threadIdx.x;                    // 0..191
    int k = count_pix[bi];
    int st = off_pix[bi];
    float4 acc = {0.f, 0.f, 0.f, 0.f};
    for (int j = 0; j < k; ++j) {
        int i = list_pix[st + j];
        int tok = idx_agg[i];
        float4 v = ((const float4*)(x + ((size_t)(b * NN + tok)) * CC))[c4];
        acc.x += v.x; acc.y += v.y; acc.z += v.z; acc.w += v.w;
    }
    float inv = 1.0f / ((float)k + EPS);
    acc.x *= inv; acc.y *= inv; acc.z *= inv; acc.w *= inv;
    VecIO<T1>::store(xm + (size_t)bi * CC, c4, acc);
}

// ---------------------------------------------------------------------------
// K2: depthwise 3x3 conv + bias, per-pixel block, weights in registers.
//     XCD-chunked swizzle: each XCD gets a contiguous half-image for L2 halo reuse.
template <typename T1, typename T2>
__global__ __launch_bounds__(192) void k_conv(const T1* __restrict__ xm,
                                              const float* __restrict__ w_dw,
                                              const float* __restrict__ b_dw,
                                              T2* __restrict__ ym) {
    int bi = blockIdx.x;
    bi = (bi & 7) * (NPIX / 8) + (bi >> 3);  // bijective: 65536 % 8 == 0
    int b = bi >> 14;
    int pix = bi & 16383;
    int ph = pix >> 7;
    int pw = pix & 127;
    int c4 = threadIdx.x;
    int c0 = c4 * 4;

    float wreg[36];                          // 4 channels x 9 taps
    {
        const float4* wp = (const float4*)(w_dw + (size_t)c0 * 9);  // 144B-aligned
#pragma unroll
        for (int j = 0; j < 9; ++j) ((float4*)wreg)[j] = wp[j];
    }
    float4 acc = ((const float4*)b_dw)[c4];
    const T1* base = xm + (size_t)(b << 14) * CC;
#pragma unroll
    for (int ky = -1; ky <= 1; ++ky) {
        int py = ph + ky;
        if (py < 0 || py >= HH) continue;
#pragma unroll
        for (int kx = -1; kx <= 1; ++kx) {
            int px = pw + kx;
            if (px < 0 || px >= WW) continue;
            int t = (ky + 1) * 3 + (kx + 1);
            float4 v = VecIO<T1>::load(base + (size_t)(py * WW + px) * CC, c4);
            acc.x += v.x * wreg[0 * 9 + t];
            acc.y += v.y * wreg[1 * 9 + t];
            acc.z += v.z * wreg[2 * 9 + t];
            acc.w += v.w * wreg[3 * 9 + t];
        }
    }
    VecIO<T2>::store(ym + (size_t)bi * CC, c4, acc);
}

// ---------------------------------------------------------------------------
// K3: per-token gather of its samples' conv rows, weighted avg, fused skip.
//     grid = NTOK, 192 thr.  No atomics, out written once.
template <typename T2>
__global__ __launch_bounds__(192) void k_token(const T2* __restrict__ ym,
                                               const float* __restrict__ x,
                                               const float* __restrict__ agg_w,
                                               const int* __restrict__ idx_hw,
                                               const int* __restrict__ count_tok,
                                               const int* __restrict__ off_tok,
                                               const int* __restrict__ list_tok,
                                               const float* __restrict__ w_skip,
                                               float* __restrict__ out) {
    int bi = blockIdx.x;                     // b*NN + tok
    int b = bi >> 12;                        // NN = 4096
    int c4 = threadIdx.x;
    int k = count_tok[bi];
    int st = off_tok[bi];
    float4 acc = {0.f, 0.f, 0.f, 0.f};
    float tw = 0.f;
    for (int j = 0; j < k; ++j) {
        int i = list_tok[st + j];
        float w = agg_w[i];
        int pix = idx_hw[i];
        float4 v = VecIO<T2>::load(ym + (size_t)((b << 14) + pix) * CC, c4);
        acc.x += w * v.x; acc.y += w * v.y; acc.z += w * v.z; acc.w += w * v.w;
        tw += w;
    }
    float inv = 1.0f / (tw + EPS);
    float4 xv = ((const float4*)(x + (size_t)bi * CC))[c4];
    float4 ws = ((const float4*)w_skip)[c4];
    float4 o;
    o.x = acc.x * inv + xv.x * ws.x;
    o.y = acc.y * inv + xv.y * ws.y;
    o.z = acc.z * inv + xv.z * ws.z;
    o.w = acc.w * inv + xv.w * ws.w;
    ((float4*)(out + (size_t)bi * CC))[c4] = o;
}

// ---------------------------------------------------------------------------
template <typename T1, typename T2>
static void run_pipeline(const float* x, const float* loc, const int* idx_agg,
                         const float* agg_w, const float* w_dw, const float* b_dw,
                         const float* w_skip, float* out, char* ws, hipStream_t stream) {
    size_t off = 0;
    // zeroed region (one memset): counts + fill cursors
    int* count_pix = (int*)(ws + off); off += (size_t)NPIX * 4;
    int* fill_pix  = (int*)(ws + off); off += (size_t)NPIX * 4;
    int* count_tok = (int*)(ws + off); off += (size_t)NTOK * 4;
    int* fill_tok  = (int*)(ws + off); off += (size_t)NTOK * 4;
    size_t zero_bytes = off;
    // fully-written regions
    int* idx_hw   = (int*)(ws + off); off += (size_t)NSAMP * 4;
    int* off_pix  = (int*)(ws + off); off += (size_t)NPIX * 4;
    int* list_pix = (int*)(ws + off); off += (size_t)NSAMP * 4;
    int* off_tok  = (int*)(ws + off); off += (size_t)NTOK * 4;
    int* list_tok = (int*)(ws + off); off += (size_t)NSAMP * 4;
    T1* xm = (T1*)(ws + off); off += (size_t)NPIX * CC * sizeof(T1);
    T2* ym = (T2*)(ws + off); off += (size_t)NPIX * CC * sizeof(T2);

    hipMemsetAsync(ws, 0, zero_bytes, stream);

    hipLaunchKernelGGL(k_idx, dim3(NSAMP / 256), dim3(256), 0, stream,
                       loc, idx_agg, idx_hw, count_pix, count_tok);
    hipLaunchKernelGGL(k_scan_excl, dim3(1), dim3(1024), 0, stream,
                       count_pix, off_pix, NPIX);
    hipLaunchKernelGGL(k_scan_excl, dim3(1), dim3(1024), 0, stream,
                       count_tok, off_tok, NTOK);
    hipLaunchKernelGGL(k_fill, dim3(NSAMP / 256), dim3(256), 0, stream,
                       idx_hw, idx_agg, off_pix, fill_pix, list_pix,
                       off_tok, fill_tok, list_tok);
    hipLaunchKernelGGL((k_xmap<T1>), dim3(NPIX), dim3(192), 0, stream,
                       x, idx_agg, count_pix, off_pix, list_pix, xm);
    hipLaunchKernelGGL((k_conv<T1, T2>), dim3(NPIX), dim3(192), 0, stream,
                       xm, w_dw, b_dw, ym);
    hipLaunchKernelGGL((k_token<T2>), dim3(NTOK), dim3(192), 0, stream,
                       ym, x, agg_w, idx_hw, count_tok, off_tok, list_tok,
                       w_skip, out);
}

// ---------------------------------------------------------------------------
extern "C" void kernel_launch(void* const* d_in, const int* in_sizes, int n_in,
                              void* d_out, int out_size, void* d_ws, size_t ws_size,
                              hipStream_t stream) {
    const float* x       = (const float*)d_in[0];   // [B,N,C]
    const float* loc     = (const float*)d_in[1];   // [B,N0,2]
    const int*   idx_agg = (const int*)d_in[2];     // [B,N0]
    const float* agg_w   = (const float*)d_in[3];   // [B,N0]
    const float* w_dw    = (const float*)d_in[6];   // [C,1,3,3]
    const float* b_dw    = (const float*)d_in[7];   // [C]
    const float* w_skip  = (const float*)d_in[8];   // [C]
    float* out = (float*)d_out;
    char* ws = (char*)d_ws;

    const size_t small = (size_t)NPIX * 4 * 3 + (size_t)NTOK * 4 * 3 +
                         (size_t)NSAMP * 4 * 3;     // counts/fills/offs/lists/idx
    const size_t mapElems = (size_t)NPIX * CC;      // 50,331,648
    const size_t need_mixed = small + mapElems * 4 + mapElems * 2;  // ~303 MB

    if (ws_size >= need_mixed) {
        // f32 x_map (full conv-input precision) + bf16 y_map (L3-resident for K3)
        run_pipeline<float, ushort>(x, loc, idx_agg, agg_w, w_dw, b_dw, w_skip,
                                    out, ws, stream);
    } else {
        // bf16 both maps (~203 MB)
        run_pipeline<ushort, ushort>(x, loc, idx_agg, agg_w, w_dw, b_dw, w_skip,
                                     out, ws, stream);
    }
}

// Round 4
// 258.148 us; speedup vs baseline: 5.5223x; 1.5246x over previous
//
#include <hip/hip_runtime.h>
#include <hip/hip_bf16.h>

// Problem constants: B=4, N=4096, C=768, H=W=128, N0=H*W=16384
#define BB 4
#define NN 4096
#define CC 768
#define HH 128
#define WW 128
#define N0 (HH * WW)
#define HW (HH * WW)
#define EPS 1e-6f
#define NSAMP (BB * N0)          // 65536
#define NPIX  (BB * HW)          // 65536
#define NTOK  (BB * NN)          // 16384

// conv tiling: 8x8 pixel tile x 128-channel slice, bf16 LDS halo tile
#define TP 8
#define CSUB 128
#define TROWU 132                // ushorts per (row,col) cell (264B, 8B-aligned)
#define NTILE (HH / TP)          // 16
#define CONV_BLOCKS (BB * (CC / CSUB) * NTILE * NTILE)   // 6144

// ---------------------------------------------------------------------------
__device__ inline float bf2f(ushort u) {
    unsigned v = ((unsigned)u) << 16;
    return __uint_as_float(v);
}
__device__ inline ushort f2bf(float f) {
    __hip_bfloat16 h = __float2bfloat16(f);   // RNE
    return *reinterpret_cast<ushort*>(&h);
}
__device__ inline float4 us4_to_f4(ushort4 u) {
    float4 r;
    r.x = bf2f(u.x); r.y = bf2f(u.y); r.z = bf2f(u.z); r.w = bf2f(u.w);
    return r;
}

// ---------------------------------------------------------------------------
// K0a: pixel index per sample + integer counts per pixel segment and token segment
__global__ void k_idx(const float* __restrict__ loc,
                      const int* __restrict__ idx_agg,
                      int* __restrict__ idx_hw,
                      int* __restrict__ count_pix,
                      int* __restrict__ count_tok) {
    int i = blockIdx.x * blockDim.x + threadIdx.x;
    if (i >= NSAMP) return;
    float lx = loc[2 * i + 0];
    float ly = loc[2 * i + 1];
    float fx = 0.5f * (lx + 1.0f) * (float)WW - 0.5f;
    float fy = 0.5f * (ly + 1.0f) * (float)HH - 0.5f;
    int px = (int)rintf(fx);                 // round-half-even == jnp.round
    int py = (int)rintf(fy);
    px = min(max(px, 0), WW - 1);
    py = min(max(py, 0), HH - 1);
    int pix = py * WW + px;
    idx_hw[i] = pix;
    int b = i >> 14;                         // N0 = 16384
    atomicAdd(&count_pix[(b << 14) + pix], 1);
    atomicAdd(&count_tok[(b << 12) + idx_agg[i]], 1);
}

// ---------------------------------------------------------------------------
// K0b: exclusive scans for both segment tables in one launch (2 blocks)
__global__ void k_scan_both(const int* __restrict__ cnt_pix, int* __restrict__ off_pix,
                            const int* __restrict__ cnt_tok, int* __restrict__ off_tok) {
    __shared__ int sh[1024];
    const int* cnt = (blockIdx.x == 0) ? cnt_pix : cnt_tok;
    int* off       = (blockIdx.x == 0) ? off_pix : off_tok;
    int n          = (blockIdx.x == 0) ? NPIX : NTOK;
    int t = threadIdx.x;                     // 1024 threads
    int chunk = (n + 1023) >> 10;
    int lo = t * chunk;
    int hi = min(n, lo + chunk);
    int s = 0;
    for (int k = lo; k < hi; ++k) s += cnt[k];
    sh[t] = s;
    __syncthreads();
    for (int d = 1; d < 1024; d <<= 1) {
        int v = (t >= d) ? sh[t - d] : 0;
        __syncthreads();
        sh[t] += v;
        __syncthreads();
    }
    int run = (t == 0) ? 0 : sh[t - 1];      // exclusive prefix of this chunk
    for (int k = lo; k < hi; ++k) {
        off[k] = run;
        run += cnt[k];
    }
}

// ---------------------------------------------------------------------------
// K0c: fill CSR sample lists (pixel-ordered and token-ordered)
__global__ void k_fill(const int* __restrict__ idx_hw,
                       const int* __restrict__ idx_agg,
                       const int* __restrict__ off_pix, int* __restrict__ fill_pix,
                       int* __restrict__ list_pix,
                       const int* __restrict__ off_tok, int* __restrict__ fill_tok,
                       int* __restrict__ list_tok) {
    int i = blockIdx.x * blockDim.x + threadIdx.x;
    if (i >= NSAMP) return;
    int b = i >> 14;
    int sp = (b << 14) + idx_hw[i];
    int p = atomicAdd(&fill_pix[sp], 1);
    list_pix[off_pix[sp] + p] = i;
    int st = (b << 12) + idx_agg[i];
    int q = atomicAdd(&fill_tok[st], 1);
    list_tok[off_tok[st] + q] = i;
}

// ---------------------------------------------------------------------------
// K1: build normalized pixel map via gather (no atomics), bf16 output.
__global__ __launch_bounds__(192) void k_xmap(const float* __restrict__ x,
                                              const int* __restrict__ idx_agg,
                                              const int* __restrict__ count_pix,
                                              const int* __restrict__ off_pix,
                                              const int* __restrict__ list_pix,
                                              ushort* __restrict__ xm) {
    int bi = blockIdx.x;                     // b*HW + pix
    int b = bi >> 14;
    int c4 = threadIdx.x;                    // 0..191
    int k = count_pix[bi];
    int st = off_pix[bi];
    float4 acc = {0.f, 0.f, 0.f, 0.f};
    for (int j = 0; j < k; ++j) {
        int i = list_pix[st + j];
        int tok = idx_agg[i];
        float4 v = ((const float4*)(x + ((size_t)(b * NN + tok)) * CC))[c4];
        acc.x += v.x; acc.y += v.y; acc.z += v.z; acc.w += v.w;
    }
    float inv = 1.0f / ((float)k + EPS);
    ushort4 o;
    o.x = f2bf(acc.x * inv); o.y = f2bf(acc.y * inv);
    o.z = f2bf(acc.z * inv); o.w = f2bf(acc.w * inv);
    ((ushort4*)(xm + (size_t)bi * CC))[c4] = o;
}

// ---------------------------------------------------------------------------
// K2: depthwise 3x3 conv + bias, LDS-tiled (8x8 pixels x 128 ch per block),
//     bf16 halo tile in LDS, register sliding window down the tile.
__global__ __launch_bounds__(256, 4) void k_conv(const ushort* __restrict__ xm,
                                                 const float* __restrict__ w_dw,
                                                 const float* __restrict__ b_dw,
                                                 ushort* __restrict__ ym) {
    __shared__ ushort tile[(TP + 2) * (TP + 2) * TROWU];   // 10*10*132*2 = 26.4 KB

    int f = blockIdx.x;
    f = (f & 7) * (CONV_BLOCKS / 8) + (f >> 3);            // bijective XCD swizzle
    int tx = f & 15;
    int ty = (f >> 4) & 15;
    int cblk = (f >> 8) % 6;
    int b = f / 1536;
    int tid = threadIdx.x;

    int c0g = cblk * CSUB;                                 // global channel base
    const ushort* src = xm + (size_t)(b << 14) * CC + c0g;

    // ---- stage 10x10 bf16 halo tile (zero-padded at image edges) ----
    for (int idx = tid; idx < (TP + 2) * (TP + 2) * (CSUB / 4); idx += 256) {
        int lc = idx & 31;                                 // ushort4 within cell
        int cell = idx >> 5;                               // 0..99
        int r = cell / (TP + 2);
        int c = cell % (TP + 2);
        int gy = ty * TP + r - 1;
        int gx = tx * TP + c - 1;
        ushort4 v = {0, 0, 0, 0};
        if (gy >= 0 && gy < HH && gx >= 0 && gx < WW) {
            v = ((const ushort4*)(src + (size_t)(gy * WW + gx) * CC))[lc];
        }
        ((ushort4*)(tile + (size_t)cell * TROWU))[lc] = v;
    }
    __syncthreads();

    // ---- per-thread: 4 channels (c4), one pixel column (px), walk 8 rows ----
    int c4 = tid & 31;
    int px = tid >> 5;                                     // 0..7

    float wreg[36];                                        // 4 ch x 9 taps
    {
        const float4* wp = (const float4*)(w_dw + (size_t)(c0g + c4 * 4) * 9);
#pragma unroll
        for (int j = 0; j < 9; ++j) ((float4*)wreg)[j] = wp[j];
    }
    float4 bias = ((const float4*)(b_dw + c0g))[c4];

    float4 a[3][3];                                        // rows oy..oy+2, cols px..px+2
#pragma unroll
    for (int i = 0; i < 2; ++i)
#pragma unroll
        for (int j = 0; j < 3; ++j)
            a[i][j] = us4_to_f4(((const ushort4*)(tile + (size_t)(i * (TP + 2) + px + j) * TROWU))[c4]);

    ushort* dst_base = ym + (size_t)((b << 14) + (ty * TP) * WW + tx * TP + px) * CC
                       + c0g;

#pragma unroll
    for (int oy = 0; oy < TP; ++oy) {
#pragma unroll
        for (int j = 0; j < 3; ++j)
            a[2][j] = us4_to_f4(((const ushort4*)(tile + (size_t)((oy + 2) * (TP + 2) + px + j) * TROWU))[c4]);

        float4 acc = bias;
#pragma unroll
        for (int i = 0; i < 3; ++i) {
#pragma unroll
            for (int j = 0; j < 3; ++j) {
                int t = i * 3 + j;
                acc.x += a[i][j].x * wreg[0 * 9 + t];
                acc.y += a[i][j].y * wreg[1 * 9 + t];
                acc.z += a[i][j].z * wreg[2 * 9 + t];
                acc.w += a[i][j].w * wreg[3 * 9 + t];
            }
        }
        ushort4 o;
        o.x = f2bf(acc.x); o.y = f2bf(acc.y); o.z = f2bf(acc.z); o.w = f2bf(acc.w);
        ((ushort4*)(dst_base + (size_t)oy * WW * CC))[c4] = o;

#pragma unroll
        for (int j = 0; j < 3; ++j) {
            a[0][j] = a[1][j];
            a[1][j] = a[2][j];
        }
    }
}

// ---------------------------------------------------------------------------
// K3: per-token gather of its samples' conv rows, weighted avg, fused skip.
__global__ __launch_bounds__(192) void k_token(const ushort* __restrict__ ym,
                                               const float* __restrict__ x,
                                               const float* __restrict__ agg_w,
                                               const int* __restrict__ idx_hw,
                                               const int* __restrict__ count_tok,
                                               const int* __restrict__ off_tok,
                                               const int* __restrict__ list_tok,
                                               const float* __restrict__ w_skip,
                                               float* __restrict__ out) {
    int bi = blockIdx.x;                     // b*NN + tok
    int b = bi >> 12;                        // NN = 4096
    int c4 = threadIdx.x;
    int k = count_tok[bi];
    int st = off_tok[bi];
    float4 acc = {0.f, 0.f, 0.f, 0.f};
    float tw = 0.f;
    for (int j = 0; j < k; ++j) {
        int i = list_tok[st + j];
        float w = agg_w[i];
        int pix = idx_hw[i];
        float4 v = us4_to_f4(((const ushort4*)(ym + (size_t)((b << 14) + pix) * CC))[c4]);
        acc.x += w * v.x; acc.y += w * v.y; acc.z += w * v.z; acc.w += w * v.w;
        tw += w;
    }
    float inv = 1.0f / (tw + EPS);
    float4 xv = ((const float4*)(x + (size_t)bi * CC))[c4];
    float4 ws = ((const float4*)w_skip)[c4];
    float4 o;
    o.x = acc.x * inv + xv.x * ws.x;
    o.y = acc.y * inv + xv.y * ws.y;
    o.z = acc.z * inv + xv.z * ws.z;
    o.w = acc.w * inv + xv.w * ws.w;
    ((float4*)(out + (size_t)bi * CC))[c4] = o;
}

// ---------------------------------------------------------------------------
extern "C" void kernel_launch(void* const* d_in, const int* in_sizes, int n_in,
                              void* d_out, int out_size, void* d_ws, size_t ws_size,
                              hipStream_t stream) {
    const float* x       = (const float*)d_in[0];   // [B,N,C]
    const float* loc     = (const float*)d_in[1];   // [B,N0,2]
    const int*   idx_agg = (const int*)d_in[2];     // [B,N0]
    const float* agg_w   = (const float*)d_in[3];   // [B,N0]
    const float* w_dw    = (const float*)d_in[6];   // [C,1,3,3]
    const float* b_dw    = (const float*)d_in[7];   // [C]
    const float* w_skip  = (const float*)d_in[8];   // [C]
    float* out = (float*)d_out;
    char* ws = (char*)d_ws;

    size_t off = 0;
    // zeroed region (one small memset): counts + fill cursors
    int* count_pix = (int*)(ws + off); off += (size_t)NPIX * 4;
    int* fill_pix  = (int*)(ws + off); off += (size_t)NPIX * 4;
    int* count_tok = (int*)(ws + off); off += (size_t)NTOK * 4;
    int* fill_tok  = (int*)(ws + off); off += (size_t)NTOK * 4;
    size_t zero_bytes = off;
    // fully-written regions
    int* idx_hw   = (int*)(ws + off); off += (size_t)NSAMP * 4;
    int* off_pix  = (int*)(ws + off); off += (size_t)NPIX * 4;
    int* list_pix = (int*)(ws + off); off += (size_t)NSAMP * 4;
    int* off_tok  = (int*)(ws + off); off += (size_t)NTOK * 4;
    int* list_tok = (int*)(ws + off); off += (size_t)NSAMP * 4;
    ushort* xm = (ushort*)(ws + off); off += (size_t)NPIX * CC * 2;   // 100.7 MB bf16
    ushort* ym = (ushort*)(ws + off); off += (size_t)NPIX * CC * 2;   // 100.7 MB bf16
    // total ~202.7 MB — within the proven-safe workspace budget (R0 used 252 MB)

    hipMemsetAsync(ws, 0, zero_bytes, stream);

    hipLaunchKernelGGL(k_idx, dim3(NSAMP / 256), dim3(256), 0, stream,
                       loc, idx_agg, idx_hw, count_pix, count_tok);
    hipLaunchKernelGGL(k_scan_both, dim3(2), dim3(1024), 0, stream,
                       count_pix, off_pix, count_tok, off_tok);
    hipLaunchKernelGGL(k_fill, dim3(NSAMP / 256), dim3(256), 0, stream,
                       idx_hw, idx_agg, off_pix, fill_pix, list_pix,
                       off_tok, fill_tok, list_tok);
    hipLaunchKernelGGL(k_xmap, dim3(NPIX), dim3(192), 0, stream,
                       x, idx_agg, count_pix, off_pix, list_pix, xm);
    hipLaunchKernelGGL(k_conv, dim3(CONV_BLOCKS), dim3(256), 0, stream,
                       xm, w_dw, b_dw, ym);
    hipLaunchKernelGGL(k_token, dim3(NTOK), dim3(192), 0, stream,
                       ym, x, agg_w, idx_hw, count_tok, off_tok, list_tok,
                       w_skip, out);
}

// Round 5
// 177.536 us; speedup vs baseline: 8.0297x; 1.4541x over previous
//
#include <hip/hip_runtime.h>
#include <hip/hip_bf16.h>

// Problem constants: B=4, N=4096, C=768, H=W=128, N0=H*W=16384
#define BB 4
#define NN 4096
#define CC 768
#define HH 128
#define WW 128
#define N0 (HH * WW)
#define HW (HH * WW)
#define EPS 1e-6f
#define NSAMP (BB * N0)          // 65536
#define NPIX  (BB * HW)          // 65536
#define NTOK  (BB * NN)          // 16384

// conv tiling: 8x8 pixel tile x 128-channel slice, bf16 LDS halo tile
#define TP 8
#define CSUB 128
#define TROWU 132                // ushorts per (row,col) cell (264B, 8B-aligned)
#define NTILE (HH / TP)          // 16
#define CONV_BLOCKS (BB * (CC / CSUB) * NTILE * NTILE)   // 6144

// ---------------------------------------------------------------------------
__device__ inline float bf2f(ushort u) {
    unsigned v = ((unsigned)u) << 16;
    return __uint_as_float(v);
}
__device__ inline ushort f2bf(float f) {
    __hip_bfloat16 h = __float2bfloat16(f);   // RNE
    return *reinterpret_cast<ushort*>(&h);
}
__device__ inline float4 us4_to_f4(ushort4 u) {
    float4 r;
    r.x = bf2f(u.x); r.y = bf2f(u.y); r.z = bf2f(u.z); r.w = bf2f(u.w);
    return r;
}

// ---------------------------------------------------------------------------
// K0a: pixel index per sample + integer counts per pixel segment and token segment
__global__ void k_idx(const float* __restrict__ loc,
                      const int* __restrict__ idx_agg,
                      int* __restrict__ idx_hw,
                      int* __restrict__ count_pix,
                      int* __restrict__ count_tok) {
    int i = blockIdx.x * blockDim.x + threadIdx.x;
    if (i >= NSAMP) return;
    float lx = loc[2 * i + 0];
    float ly = loc[2 * i + 1];
    float fx = 0.5f * (lx + 1.0f) * (float)WW - 0.5f;
    float fy = 0.5f * (ly + 1.0f) * (float)HH - 0.5f;
    int px = (int)rintf(fx);                 // round-half-even == jnp.round
    int py = (int)rintf(fy);
    px = min(max(px, 0), WW - 1);
    py = min(max(py, 0), HH - 1);
    int pix = py * WW + px;
    idx_hw[i] = pix;
    int b = i >> 14;                         // N0 = 16384
    atomicAdd(&count_pix[(b << 14) + pix], 1);
    atomicAdd(&count_tok[(b << 12) + idx_agg[i]], 1);
}

// ---------------------------------------------------------------------------
// K0b: 8 independent segment scans (4 pix batches, 4 tok batches).
// Key fact: every batch segment of BOTH tables sums to exactly N0=16384
// samples, so segment-start offsets are statically b*16384. Coalesced tiled
// block scan: wave shfl_up + 16-partial LDS scan + running total.
__global__ __launch_bounds__(1024) void k_scan(const int* __restrict__ cnt_pix,
                                               int* __restrict__ off_pix,
                                               const int* __restrict__ cnt_tok,
                                               int* __restrict__ off_tok) {
    __shared__ int wpart[16];
    __shared__ int run_sh;
    int bid = blockIdx.x;                    // 0..3 pix, 4..7 tok
    const int* cnt;
    int* off;
    int n, base, vbase;
    if (bid < 4) {
        cnt = cnt_pix; off = off_pix; n = HW;
        base = bid << 14; vbase = bid << 14;
    } else {
        cnt = cnt_tok; off = off_tok; n = NN;
        base = (bid - 4) << 12; vbase = (bid - 4) << 14;
    }
    int t = threadIdx.x;
    int lane = t & 63;
    int wid = t >> 6;                        // 0..15
    if (t == 0) run_sh = 0;
    __syncthreads();
    for (int it = 0; it < n; it += 1024) {
        int idx = it + t;
        int v = (idx < n) ? cnt[base + idx] : 0;
        int s = v;                           // inclusive wave scan
#pragma unroll
        for (int d = 1; d < 64; d <<= 1) {
            int u = __shfl_up(s, d, 64);
            if (lane >= d) s += u;
        }
        if (lane == 63) wpart[wid] = s;
        __syncthreads();
        if (wid == 0) {                      // scan the 16 wave partials
            int p = (lane < 16) ? wpart[lane] : 0;
#pragma unroll
            for (int d = 1; d < 16; d <<= 1) {
                int u = __shfl_up(p, d, 64);
                if (lane >= d) p += u;
            }
            if (lane < 16) wpart[lane] = p;
        }
        __syncthreads();
        int wbase = (wid == 0) ? 0 : wpart[wid - 1];
        int run = run_sh;
        if (idx < n) off[base + idx] = vbase + run + wbase + s - v;  // exclusive
        __syncthreads();                     // all read run_sh before update
        if (t == 0) run_sh = run + wpart[15];
        __syncthreads();
    }
}

// ---------------------------------------------------------------------------
// K0c: fill CSR sample lists (pixel-ordered and token-ordered)
__global__ void k_fill(const int* __restrict__ idx_hw,
                       const int* __restrict__ idx_agg,
                       const int* __restrict__ off_pix, int* __restrict__ fill_pix,
                       int* __restrict__ list_pix,
                       const int* __restrict__ off_tok, int* __restrict__ fill_tok,
                       int* __restrict__ list_tok) {
    int i = blockIdx.x * blockDim.x + threadIdx.x;
    if (i >= NSAMP) return;
    int b = i >> 14;
    int sp = (b << 14) + idx_hw[i];
    int p = atomicAdd(&fill_pix[sp], 1);
    list_pix[off_pix[sp] + p] = i;
    int st = (b << 12) + idx_agg[i];
    int q = atomicAdd(&fill_tok[st], 1);
    list_tok[off_tok[st] + q] = i;
}

// ---------------------------------------------------------------------------
// K1: build normalized pixel map via gather (no atomics), bf16 output.
__global__ __launch_bounds__(192) void k_xmap(const float* __restrict__ x,
                                              const int* __restrict__ idx_agg,
                                              const int* __restrict__ count_pix,
                                              const int* __restrict__ off_pix,
                                              const int* __restrict__ list_pix,
                                              ushort* __restrict__ xm) {
    int bi = blockIdx.x;                     // b*HW + pix
    int b = bi >> 14;
    int c4 = threadIdx.x;                    // 0..191
    int k = count_pix[bi];
    int st = off_pix[bi];
    float4 acc = {0.f, 0.f, 0.f, 0.f};
    for (int j = 0; j < k; ++j) {
        int i = list_pix[st + j];
        int tok = idx_agg[i];
        float4 v = ((const float4*)(x + ((size_t)(b * NN + tok)) * CC))[c4];
        acc.x += v.x; acc.y += v.y; acc.z += v.z; acc.w += v.w;
    }
    float inv = 1.0f / ((float)k + EPS);
    ushort4 o;
    o.x = f2bf(acc.x * inv); o.y = f2bf(acc.y * inv);
    o.z = f2bf(acc.z * inv); o.w = f2bf(acc.w * inv);
    ((ushort4*)(xm + (size_t)bi * CC))[c4] = o;
}

// ---------------------------------------------------------------------------
// K2: depthwise 3x3 conv + bias, LDS-tiled (8x8 pixels x 128 ch per block),
//     bf16 halo tile in LDS, register sliding window down the tile.
__global__ __launch_bounds__(256, 4) void k_conv(const ushort* __restrict__ xm,
                                                 const float* __restrict__ w_dw,
                                                 const float* __restrict__ b_dw,
                                                 ushort* __restrict__ ym) {
    __shared__ ushort tile[(TP + 2) * (TP + 2) * TROWU];   // 10*10*132*2 = 26.4 KB

    int f = blockIdx.x;
    f = (f & 7) * (CONV_BLOCKS / 8) + (f >> 3);            // bijective XCD swizzle
    int tx = f & 15;
    int ty = (f >> 4) & 15;
    int cblk = (f >> 8) % 6;
    int b = f / 1536;
    int tid = threadIdx.x;

    int c0g = cblk * CSUB;                                 // global channel base
    const ushort* src = xm + (size_t)(b << 14) * CC + c0g;

    // ---- stage 10x10 bf16 halo tile (zero-padded at image edges) ----
    for (int idx = tid; idx < (TP + 2) * (TP + 2) * (CSUB / 4); idx += 256) {
        int lc = idx & 31;                                 // ushort4 within cell
        int cell = idx >> 5;                               // 0..99
        int r = cell / (TP + 2);
        int c = cell % (TP + 2);
        int gy = ty * TP + r - 1;
        int gx = tx * TP + c - 1;
        ushort4 v = {0, 0, 0, 0};
        if (gy >= 0 && gy < HH && gx >= 0 && gx < WW) {
            v = ((const ushort4*)(src + (size_t)(gy * WW + gx) * CC))[lc];
        }
        ((ushort4*)(tile + (size_t)cell * TROWU))[lc] = v;
    }
    __syncthreads();

    // ---- per-thread: 4 channels (c4), one pixel column (px), walk 8 rows ----
    int c4 = tid & 31;
    int px = tid >> 5;                                     // 0..7

    float wreg[36];                                        // 4 ch x 9 taps
    {
        const float4* wp = (const float4*)(w_dw + (size_t)(c0g + c4 * 4) * 9);
#pragma unroll
        for (int j = 0; j < 9; ++j) ((float4*)wreg)[j] = wp[j];
    }
    float4 bias = ((const float4*)(b_dw + c0g))[c4];

    float4 a[3][3];                                        // rows oy..oy+2, cols px..px+2
#pragma unroll
    for (int i = 0; i < 2; ++i)
#pragma unroll
        for (int j = 0; j < 3; ++j)
            a[i][j] = us4_to_f4(((const ushort4*)(tile + (size_t)(i * (TP + 2) + px + j) * TROWU))[c4]);

    ushort* dst_base = ym + (size_t)((b << 14) + (ty * TP) * WW + tx * TP + px) * CC
                       + c0g;

#pragma unroll
    for (int oy = 0; oy < TP; ++oy) {
#pragma unroll
        for (int j = 0; j < 3; ++j)
            a[2][j] = us4_to_f4(((const ushort4*)(tile + (size_t)((oy + 2) * (TP + 2) + px + j) * TROWU))[c4]);

        float4 acc = bias;
#pragma unroll
        for (int i = 0; i < 3; ++i) {
#pragma unroll
            for (int j = 0; j < 3; ++j) {
                int t = i * 3 + j;
                acc.x += a[i][j].x * wreg[0 * 9 + t];
                acc.y += a[i][j].y * wreg[1 * 9 + t];
                acc.z += a[i][j].z * wreg[2 * 9 + t];
                acc.w += a[i][j].w * wreg[3 * 9 + t];
            }
        }
        ushort4 o;
        o.x = f2bf(acc.x); o.y = f2bf(acc.y); o.z = f2bf(acc.z); o.w = f2bf(acc.w);
        ((ushort4*)(dst_base + (size_t)oy * WW * CC))[c4] = o;

#pragma unroll
        for (int j = 0; j < 3; ++j) {
            a[0][j] = a[1][j];
            a[1][j] = a[2][j];
        }
    }
}

// ---------------------------------------------------------------------------
// K3: per-token gather of its samples' conv rows, weighted avg, fused skip.
__global__ __launch_bounds__(192) void k_token(const ushort* __restrict__ ym,
                                               const float* __restrict__ x,
                                               const float* __restrict__ agg_w,
                                               const int* __restrict__ idx_hw,
                                               const int* __restrict__ count_tok,
                                               const int* __restrict__ off_tok,
                                               const int* __restrict__ list_tok,
                                               const float* __restrict__ w_skip,
                                               float* __restrict__ out) {
    int bi = blockIdx.x;                     // b*NN + tok
    int b = bi >> 12;                        // NN = 4096
    int c4 = threadIdx.x;
    int k = count_tok[bi];
    int st = off_tok[bi];
    float4 acc = {0.f, 0.f, 0.f, 0.f};
    float tw = 0.f;
    for (int j = 0; j < k; ++j) {
        int i = list_tok[st + j];
        float w = agg_w[i];
        int pix = idx_hw[i];
        float4 v = us4_to_f4(((const ushort4*)(ym + (size_t)((b << 14) + pix) * CC))[c4]);
        acc.x += w * v.x; acc.y += w * v.y; acc.z += w * v.z; acc.w += w * v.w;
        tw += w;
    }
    float inv = 1.0f / (tw + EPS);
    float4 xv = ((const float4*)(x + (size_t)bi * CC))[c4];
    float4 ws = ((const float4*)w_skip)[c4];
    float4 o;
    o.x = acc.x * inv + xv.x * ws.x;
    o.y = acc.y * inv + xv.y * ws.y;
    o.z = acc.z * inv + xv.z * ws.z;
    o.w = acc.w * inv + xv.w * ws.w;
    ((float4*)(out + (size_t)bi * CC))[c4] = o;
}

// ---------------------------------------------------------------------------
extern "C" void kernel_launch(void* const* d_in, const int* in_sizes, int n_in,
                              void* d_out, int out_size, void* d_ws, size_t ws_size,
                              hipStream_t stream) {
    const float* x       = (const float*)d_in[0];   // [B,N,C]
    const float* loc     = (const float*)d_in[1];   // [B,N0,2]
    const int*   idx_agg = (const int*)d_in[2];     // [B,N0]
    const float* agg_w   = (const float*)d_in[3];   // [B,N0]
    const float* w_dw    = (const float*)d_in[6];   // [C,1,3,3]
    const float* b_dw    = (const float*)d_in[7];   // [C]
    const float* w_skip  = (const float*)d_in[8];   // [C]
    float* out = (float*)d_out;
    char* ws = (char*)d_ws;

    size_t off = 0;
    // zeroed region (one small memset): counts + fill cursors
    int* count_pix = (int*)(ws + off); off += (size_t)NPIX * 4;
    int* fill_pix  = (int*)(ws + off); off += (size_t)NPIX * 4;
    int* count_tok = (int*)(ws + off); off += (size_t)NTOK * 4;
    int* fill_tok  = (int*)(ws + off); off += (size_t)NTOK * 4;
    size_t zero_bytes = off;
    // fully-written regions
    int* idx_hw   = (int*)(ws + off); off += (size_t)NSAMP * 4;
    int* off_pix  = (int*)(ws + off); off += (size_t)NPIX * 4;
    int* list_pix = (int*)(ws + off); off += (size_t)NSAMP * 4;
    int* off_tok  = (int*)(ws + off); off += (size_t)NTOK * 4;
    int* list_tok = (int*)(ws + off); off += (size_t)NSAMP * 4;
    ushort* xm = (ushort*)(ws + off); off += (size_t)NPIX * CC * 2;   // 100.7 MB bf16
    ushort* ym = (ushort*)(ws + off); off += (size_t)NPIX * CC * 2;   // 100.7 MB bf16
    // total ~202.7 MB — within the proven-safe workspace budget (R0 used 252 MB)

    hipMemsetAsync(ws, 0, zero_bytes, stream);

    hipLaunchKernelGGL(k_idx, dim3(NSAMP / 256), dim3(256), 0, stream,
                       loc, idx_agg, idx_hw, count_pix, count_tok);
    hipLaunchKernelGGL(k_scan, dim3(8), dim3(1024), 0, stream,
                       count_pix, off_pix, count_tok, off_tok);
    hipLaunchKernelGGL(k_fill, dim3(NSAMP / 256), dim3(256), 0, stream,
                       idx_hw, idx_agg, off_pix, fill_pix, list_pix,
                       off_tok, fill_tok, list_tok);
    hipLaunchKernelGGL(k_xmap, dim3(NPIX), dim3(192), 0, stream,
                       x, idx_agg, count_pix, off_pix, list_pix, xm);
    hipLaunchKernelGGL(k_conv, dim3(CONV_BLOCKS), dim3(256), 0, stream,
                       xm, w_dw, b_dw, ym);
    hipLaunchKernelGGL(k_token, dim3(NTOK), dim3(192), 0, stream,
                       ym, x, agg_w, idx_hw, count_tok, off_tok, list_tok,
                       w_skip, out);
}